// Round 2
// baseline (553.122 us; speedup 1.0000x reference)
//
#include <hip/hip_runtime.h>
#include <math.h>

// CRF mean-field, fully factorized — NO O(N^2) pass.
// Single cooperative kernel (512 thr/blk) + CUSTOM manager-block grid barrier
// (release/acquire scoped atomics, padded per-block flags -> ~2-3 us/sync vs
// ~27 us/sync for cg::grid_group::sync on ROCm).
// Bilateral kernel rank-28 Taylor basis (degree 6), separable 3-D Gaussian
// convs, 5 mean-field iterations. N = 32*16*16 = 8192, C = 4.

constexpr int   NT    = 8192;
constexpr float LOG2E = 1.4426950408889634f;
constexpr float SQL2E = 1.2011224087864498f;     // sqrt(log2 e)
constexpr float INVA  = 0.2f * SQL2E;            // spatial prescale

// W rows (NT floats each):
//   0..27  : M[ab]   28..31 : sync flags area (8 KB used)   32..35 u1[c]
//   36..39 u2[c]   40 scale1  41 scale2  42..157 conv outputs
constexpr int R_M = 0, R_SY = 28, R_U1 = 32, R_U2 = 36, R_S1 = 40, R_S2 = 41, R_CV = 42;
constexpr int NBLK = 116;                         // 112 bilateral + 4 spatial vols
constexpr int PPB  = (NT + NBLK - 1) / NBLK;      // 71 points/block, pointwise phases

static __device__ __forceinline__ float ex2(float x) {
    return __builtin_amdgcn_exp2f(x);
}

__constant__ float INVSQF[7] = {1.f, 1.f, 0.70710678f, 0.40824829f,
                                0.20412415f, 0.09128709f, 0.03726780f};
// ab -> (a,b) enumeration: for k=0..6, a=k..0, b=k-a  (must match contract order)
__constant__ int AB_A[28] = {0, 1,0, 2,1,0, 3,2,1,0, 4,3,2,1,0,
                             5,4,3,2,1,0, 6,5,4,3,2,1,0};
__constant__ int AB_B[28] = {0, 0,1, 0,1,2, 0,1,2,3, 0,1,2,3,4,
                             0,1,2,3,4,5, 0,1,2,3,4,5,6};

// ------------------------- custom grid barrier ------------------------------
// sync[0] = go word; sync[16 + b*16] = arrive flag of block b (64B padded).
// Manager = block 0. Release/acquire at AGENT scope gives cross-XCD
// visibility (compiler emits buffer_wbl2/buffer_inv sc1).
static __device__ __forceinline__ void gsync(unsigned* sync, unsigned gen) {
    __syncthreads();
    if (blockIdx.x == 0) {
        if (threadIdx.x > 0 && threadIdx.x < NBLK) {
            unsigned* f = sync + 16 + threadIdx.x * 16;
            while (__hip_atomic_load(f, __ATOMIC_ACQUIRE, __HIP_MEMORY_SCOPE_AGENT) < gen) {}
        }
        __syncthreads();
        if (threadIdx.x == 0)
            __hip_atomic_store(sync, gen, __ATOMIC_RELEASE, __HIP_MEMORY_SCOPE_AGENT);
    } else {
        if (threadIdx.x == 0) {
            __hip_atomic_store(sync + 16 + blockIdx.x * 16, gen,
                               __ATOMIC_RELEASE, __HIP_MEMORY_SCOPE_AGENT);
            while (__hip_atomic_load(sync, __ATOMIC_ACQUIRE, __HIP_MEMORY_SCOPE_AGENT) < gen) {}
        }
    }
    __syncthreads();
}

// ---------------- separable 3-D Gaussian conv, 512-thread version -----------
// SP staged as SP[(n>>4)*17 + (n&15)]; caller stages, we sync first.
static __device__ __forceinline__ void conv3d_store512(float* SP,
                                                       float* __restrict__ outp,
                                                       int tid) {
    float g32[32];
#pragma unroll
    for (int d = 0; d < 32; d++) { float t = d * INVA; g32[d] = ex2(-0.5f*t*t); }
    __syncthreads();
    // z-pass: 512 rows (x,y), one per thread, stride 17
    {
        int r = tid;
        float v[16], acc[16];
#pragma unroll
        for (int z = 0; z < 16; z++) { v[z] = SP[r*17 + z]; acc[z] = 0.f; }
#pragma unroll
        for (int zp = 0; zp < 16; zp++)
#pragma unroll
            for (int z = 0; z < 16; z++) {
                int d = (z > zp) ? (z - zp) : (zp - z);
                acc[z] = fmaf(g32[d], v[zp], acc[z]);
            }
#pragma unroll
        for (int z = 0; z < 16; z++) SP[r*17 + z] = acc[z];
    }
    __syncthreads();
    // y-pass: 512 rows (x,z), one per thread, stride 17 between y's
    {
        int x = tid >> 4, z = tid & 15;
        int base = x * 272 + z;
        float v[16], acc[16];
#pragma unroll
        for (int y = 0; y < 16; y++) { v[y] = SP[base + y*17]; acc[y] = 0.f; }
#pragma unroll
        for (int yp = 0; yp < 16; yp++)
#pragma unroll
            for (int y = 0; y < 16; y++) {
                int d = (y > yp) ? (y - yp) : (yp - y);
                acc[y] = fmaf(g32[d], v[yp], acc[y]);
            }
#pragma unroll
        for (int y = 0; y < 16; y++) SP[base + y*17] = acc[y];
    }
    __syncthreads();
    // x-pass: 256 columns (y,z), 2 threads/column; h wave-uniform (tid>>8)
    // so all g32 indices stay compile-time constants (no scratch spill).
    {
        int c = tid & 255, h = tid >> 8;
        int base = (c >> 4) * 17 + (c & 15);     // 17*y + z
        float v[32];
#pragma unroll
        for (int xp = 0; xp < 32; xp++) v[xp] = SP[base + xp*272];
        float acc[16];
#pragma unroll
        for (int x0 = 0; x0 < 16; x0++) acc[x0] = 0.f;
        if (h == 0) {
#pragma unroll
            for (int xp = 0; xp < 32; xp++)
#pragma unroll
                for (int x0 = 0; x0 < 16; x0++) {
                    int d = (x0 > xp) ? (x0 - xp) : (xp - x0);
                    acc[x0] = fmaf(g32[d], v[xp], acc[x0]);
                }
#pragma unroll
            for (int x0 = 0; x0 < 16; x0++) outp[x0*256 + c] = acc[x0];
        } else {
#pragma unroll
            for (int xp = 0; xp < 32; xp++)
#pragma unroll
                for (int x0 = 0; x0 < 16; x0++) {
                    int x = x0 + 16;
                    int d = (x > xp) ? (x - xp) : (xp - x);
                    acc[x0] = fmaf(g32[d], v[xp], acc[x0]);
                }
#pragma unroll
            for (int x0 = 0; x0 < 16; x0++) outp[(x0+16)*256 + c] = acc[x0];
        }
    }
}

// ---------------- separable 3-D conv, 256-thread version (fallback path) ----
static __device__ __forceinline__ void conv3d_store256(float* SP,
                                                       float* __restrict__ outp,
                                                       int tid) {
    float g32[32];
#pragma unroll
    for (int d = 0; d < 32; d++) { float t = d * INVA; g32[d] = ex2(-0.5f*t*t); }
    __syncthreads();
#pragma unroll
    for (int rr = 0; rr < 2; rr++) {
        int r = tid + rr * 256;
        float v[16], acc[16];
#pragma unroll
        for (int z = 0; z < 16; z++) { v[z] = SP[r*17 + z]; acc[z] = 0.f; }
#pragma unroll
        for (int zp = 0; zp < 16; zp++)
#pragma unroll
            for (int z = 0; z < 16; z++) {
                int d = (z > zp) ? (z - zp) : (zp - z);
                acc[z] = fmaf(g32[d], v[zp], acc[z]);
            }
#pragma unroll
        for (int z = 0; z < 16; z++) SP[r*17 + z] = acc[z];
    }
    __syncthreads();
#pragma unroll
    for (int rr = 0; rr < 2; rr++) {
        int r = tid + rr * 256;
        int x = r >> 4, z = r & 15;
        int base = x * 272 + z;
        float v[16], acc[16];
#pragma unroll
        for (int y = 0; y < 16; y++) { v[y] = SP[base + y*17]; acc[y] = 0.f; }
#pragma unroll
        for (int yp = 0; yp < 16; yp++)
#pragma unroll
            for (int y = 0; y < 16; y++) {
                int d = (y > yp) ? (y - yp) : (yp - y);
                acc[y] = fmaf(g32[d], v[yp], acc[y]);
            }
#pragma unroll
        for (int y = 0; y < 16; y++) SP[base + y*17] = acc[y];
    }
    __syncthreads();
    {
        int base = (tid >> 4) * 17 + (tid & 15);
        float v[32], acc[32];
#pragma unroll
        for (int xp = 0; xp < 32; xp++) { v[xp] = SP[base + xp*272]; acc[xp] = 0.f; }
#pragma unroll
        for (int xp = 0; xp < 32; xp++)
#pragma unroll
            for (int x = 0; x < 32; x++) {
                int d = (x > xp) ? (x - xp) : (xp - x);
                acc[x] = fmaf(g32[d], v[xp], acc[x]);
            }
#pragma unroll
        for (int x = 0; x < 32; x++) outp[x*256 + tid] = acc[x];
    }
}

// ----------------------------- pointwise bodies -----------------------------
static __device__ __forceinline__ void init_point(float* __restrict__ W,
                                                  const float* __restrict__ lu,
                                                  int n) {
    float rs = 0.f;
#pragma unroll
    for (int ab = 0; ab < 28; ab++)
        rs = fmaf(W[(R_M+ab)*NT + n], W[(R_CV+ab)*NT + n], rs);
    float s1 = rsqrtf(rs);
    float s2 = W[R_S2*NT + n];
    W[R_S1*NT + n] = s1;
    float l0 = lu[n], l1 = lu[NT+n], l2 = lu[2*NT+n], l3 = lu[3*NT+n];
    float mx = fmaxf(fmaxf(l0,l1), fmaxf(l2,l3));
    float q0 = __expf(l0-mx), q1 = __expf(l1-mx), q2 = __expf(l2-mx), q3 = __expf(l3-mx);
    float inv = 1.f / (q0+q1+q2+q3);
    q0*=inv; q1*=inv; q2*=inv; q3*=inv;
    W[(R_U1+0)*NT+n]=q0*s1; W[(R_U1+1)*NT+n]=q1*s1; W[(R_U1+2)*NT+n]=q2*s1; W[(R_U1+3)*NT+n]=q3*s1;
    W[(R_U2+0)*NT+n]=q0*s2; W[(R_U2+1)*NT+n]=q1*s2; W[(R_U2+2)*NT+n]=q2*s2; W[(R_U2+3)*NT+n]=q3*s2;
}

static __device__ __forceinline__ void fuse_point(float* __restrict__ W,
        const float* __restrict__ lu, const float* __restrict__ compat,
        float* __restrict__ out, int n, int last) {
    float s1 = W[R_S1*NT + n], s2 = W[R_S2*NT + n];
    float q1[4] = {0.f, 0.f, 0.f, 0.f};
#pragma unroll
    for (int ab = 0; ab < 28; ab++) {
        float m = W[(R_M+ab)*NT + n];
#pragma unroll
        for (int c = 0; c < 4; c++)
            q1[c] = fmaf(m, W[(R_CV + ab*4 + c)*NT + n], q1[c]);
    }
    float comb[4];
#pragma unroll
    for (int c = 0; c < 4; c++)
        comb[c] = s1 * q1[c] + s2 * W[(R_CV + 112 + c)*NT + n];
    float q[4];
#pragma unroll
    for (int o = 0; o < 4; o++) {
        float upd = 0.f;
#pragma unroll
        for (int c = 0; c < 4; c++) upd = fmaf(compat[o*4+c], comb[c], upd);
        q[o] = lu[o*NT+n] - upd;
    }
    float mx = fmaxf(fmaxf(q[0],q[1]), fmaxf(q[2],q[3]));
    float sum = 0.f;
#pragma unroll
    for (int c = 0; c < 4; c++) { q[c] = __expf(q[c]-mx); sum += q[c]; }
    float inv = 1.f / sum;
    if (last) {
#pragma unroll
        for (int c = 0; c < 4; c++) out[c*NT+n] = q[c] * inv;
    } else {
#pragma unroll
        for (int c = 0; c < 4; c++) {
            float qq = q[c] * inv;
            W[(R_U1+c)*NT+n] = qq*s1;
            W[(R_U2+c)*NT+n] = qq*s2;
        }
    }
}

// ---------------------- zero the barrier flags (pre-kernel) -----------------
__global__ __launch_bounds__(256) void k_zero(float* __restrict__ W) {
    unsigned* sync = (unsigned*)(W + R_SY*NT);
    int g = blockIdx.x * 256 + threadIdx.x;
    if (g < 2048) sync[g] = 0u;
}

// --------------------------- the single cooperative kernel ------------------
__global__ __launch_bounds__(512) void k_crf_all(const float* __restrict__ lu,
        const float* __restrict__ feat, const float* __restrict__ compat,
        float* __restrict__ out, float* __restrict__ W) {
    __shared__ float SP[512 * 17];
    const int bid = blockIdx.x, tid = threadIdx.x;
    unsigned* sync = (unsigned*)(W + R_SY*NT);
    unsigned gen = 0;

    // ---- phase A: blocks 0..27 build + conv their own basis row (norm pass);
    //               blocks 28..115 compute closed-form scale2.
    if (bid < 28) {
        const int a = AB_A[bid], b = AB_B[bid];
        const float ca = INVSQF[a], cb = INVSQF[b];
        for (int s = tid; s < NT; s += 512) {
            float g0 = feat[s] * 0.2f, g1 = feat[NT + s] * 0.2f;
            float eg = ex2(-0.5f * LOG2E * (g0*g0 + g1*g1));
            float pa = 1.f;
            for (int i = 0; i < a; i++) pa *= g0;   // a,b wave-uniform (blockIdx)
            float pb = 1.f;
            for (int i = 0; i < b; i++) pb *= g1;
            float v = eg * pa * ca * pb * cb;
            W[(R_M + bid)*NT + s] = v;
            SP[(s >> 4)*17 + (s & 15)] = v;
        }
        conv3d_store512(SP, W + (R_CV + bid)*NT, tid);
    } else {
        const int nb = (bid - 28) * 94 + tid;       // 88 blocks x 94 >= 8192
        if (tid < 94 && nb < NT) {
            int x = nb >> 8, y = (nb >> 4) & 15, z = nb & 15;
            float Sx = 0.f, Sy = 0.f, Sz = 0.f;
            for (int j = 0; j < 32; j++) { float d = (float)(x-j)*INVA; Sx += ex2(-0.5f*d*d); }
            for (int j = 0; j < 16; j++) { float d = (float)(y-j)*INVA; Sy += ex2(-0.5f*d*d); }
            for (int j = 0; j < 16; j++) { float d = (float)(z-j)*INVA; Sz += ex2(-0.5f*d*d); }
            W[R_S2*NT + nb] = rsqrtf(Sx * Sy * Sz);
        }
    }
    gsync(sync, ++gen);

    // ---- init: rowsum contract -> scale1, q0, u1, u2
    { int n = bid * PPB + tid; if (tid < PPB && n < NT) init_point(W, lu, n); }
    gsync(sync, ++gen);

    // ---- 5 mean-field iterations: conv(116 vols) -> fuse -> repeat
    for (int it = 0; it < 5; ++it) {
        {
            const int idx = bid;
            if (idx < 112) {
                const float* Mr = W + (R_M + (idx >> 2))*NT;
                const float* ur = W + (R_U1 + (idx & 3))*NT;
                for (int s = tid; s < NT; s += 512)
                    SP[(s >> 4)*17 + (s & 15)] = Mr[s] * ur[s];
            } else {
                const float* ur = W + (R_U2 + (idx - 112))*NT;
                for (int s = tid; s < NT; s += 512)
                    SP[(s >> 4)*17 + (s & 15)] = ur[s];
            }
            conv3d_store512(SP, W + (R_CV + idx)*NT, tid);
        }
        gsync(sync, ++gen);
        { int n = bid * PPB + tid; if (tid < PPB && n < NT) fuse_point(W, lu, compat, out, n, it == 4); }
        if (it < 4) gsync(sync, ++gen);
    }
}

// --------------------------- fallback multi-kernel path ---------------------
__global__ __launch_bounds__(256) void k_setup(const float* __restrict__ feat,
                                               float* __restrict__ W) {
    int n = blockIdx.x * 256 + threadIdx.x;
    float g0 = feat[n] * 0.2f, g1 = feat[NT + n] * 0.2f;
    float eg = ex2(-0.5f * LOG2E * (g0*g0 + g1*g1));
    float p0[7], p1[7];
    p0[0] = 1.f; p1[0] = 1.f;
#pragma unroll
    for (int i = 1; i < 7; i++) { p0[i] = p0[i-1]*g0; p1[i] = p1[i-1]*g1; }
    int ab = 0;
#pragma unroll
    for (int k = 0; k <= 6; k++)
#pragma unroll
        for (int a = k; a >= 0; a--) {
            int b = k - a;
            W[(R_M + ab)*NT + n] = eg * p0[a]*INVSQF[a] * p1[b]*INVSQF[b];
            ab++;
        }
    int x = n >> 8, y = (n >> 4) & 15, z = n & 15;
    float Sx = 0.f, Sy = 0.f, Sz = 0.f;
    for (int j = 0; j < 32; j++) { float d = (float)(x-j)*INVA; Sx += ex2(-0.5f*d*d); }
    for (int j = 0; j < 16; j++) { float d = (float)(y-j)*INVA; Sy += ex2(-0.5f*d*d); }
    for (int j = 0; j < 16; j++) { float d = (float)(z-j)*INVA; Sz += ex2(-0.5f*d*d); }
    W[R_S2*NT + n] = rsqrtf(Sx * Sy * Sz);
}

__global__ __launch_bounds__(256) void k_conv(const float* __restrict__ W,
                                              float* __restrict__ Wout, int mode) {
    __shared__ float SP[512 * 17];
    const int idx = blockIdx.x;
    const int tid = threadIdx.x;
    if (mode == 0) {
        const float* src = W + (R_M + idx) * NT;
        for (int s = tid; s < NT; s += 256)
            SP[(s >> 4)*17 + (s & 15)] = src[s];
    } else if (idx < 112) {
        const float* Mr = W + (R_M + (idx >> 2)) * NT;
        const float* ur = W + (R_U1 + (idx & 3)) * NT;
        for (int s = tid; s < NT; s += 256)
            SP[(s >> 4)*17 + (s & 15)] = Mr[s] * ur[s];
    } else {
        const float* ur = W + (R_U2 + (idx - 112)) * NT;
        for (int s = tid; s < NT; s += 256)
            SP[(s >> 4)*17 + (s & 15)] = ur[s];
    }
    conv3d_store256(SP, Wout + (R_CV + idx)*NT, tid);
}

__global__ __launch_bounds__(256) void k_init(float* __restrict__ W,
                                              const float* __restrict__ lu) {
    int n = blockIdx.x * 256 + threadIdx.x;
    init_point(W, lu, n);
}

__global__ __launch_bounds__(256) void k_fuse(float* __restrict__ W,
        const float* __restrict__ lu, const float* __restrict__ compat,
        float* __restrict__ out, int last) {
    int n = blockIdx.x * 256 + threadIdx.x;
    fuse_point(W, lu, compat, out, n, last);
}

// ---------------------------------------------------------------- driver
extern "C" void kernel_launch(void* const* d_in, const int* in_sizes, int n_in,
                              void* d_out, int out_size, void* d_ws, size_t ws_size,
                              hipStream_t stream) {
    const float* lu     = (const float*)d_in[0];
    const float* feat   = (const float*)d_in[1];
    const float* compat = (const float*)d_in[2];
    float* out = (float*)d_out;
    float* W   = (float*)d_ws;     // needs 158*NT*4 = 5.2 MB

    k_zero<<<dim3(8), dim3(256), 0, stream>>>(W);   // zero barrier flags

    void* args[] = {(void*)&lu, (void*)&feat, (void*)&compat, (void*)&out, (void*)&W};
    hipError_t rc = hipLaunchCooperativeKernel((const void*)k_crf_all,
                                               dim3(NBLK), dim3(512), args, 0, stream);
    if (rc != hipSuccess) {
        (void)hipGetLastError();   // clear, fall back to multi-launch path
        k_setup<<<dim3(32), dim3(256), 0, stream>>>(feat, W);
        k_conv <<<dim3(28), dim3(256), 0, stream>>>(W, W, 0);
        k_init <<<dim3(32), dim3(256), 0, stream>>>(W, lu);
        for (int it = 0; it < 5; it++) {
            k_conv<<<dim3(116), dim3(256), 0, stream>>>(W, W, 1);
            k_fuse<<<dim3(32),  dim3(256), 0, stream>>>(W, lu, compat, out, it == 4);
        }
    }
}

// Round 3
// 449.180 us; speedup vs baseline: 1.2314x; 1.2314x over previous
//
#include <hip/hip_runtime.h>
#include <math.h>

// CRF mean-field, fully factorized — NO O(N^2) pass.
// Single persistent kernel + custom grid barrier built on RELAXED atomic RMWs
// (no per-poll cache ops — round 2 showed acquire-load polling causes an L2
// invalidate storm: 87 MB writes, 490 us). Cache coherence paid exactly once
// per block per barrier via one __threadfence() pair on thread 0.
// Bilateral kernel rank-28 Taylor basis (degree 6), separable 3-D Gaussian
// convs, 5 mean-field iterations. N = 32*16*16 = 8192, C = 4.

constexpr int   NT    = 8192;
constexpr float LOG2E = 1.4426950408889634f;
constexpr float SQL2E = 1.2011224087864498f;     // sqrt(log2 e)
constexpr float INVA  = 0.2f * SQL2E;            // spatial prescale

// W rows (NT floats each):
//   0..27  : M[ab]   28..31 : sync flags area   32..35 u1[c]
//   36..39 u2[c]   40 scale1  41 scale2  42..157 conv outputs
constexpr int R_M = 0, R_SY = 28, R_U1 = 32, R_U2 = 36, R_S1 = 40, R_S2 = 41, R_CV = 42;
constexpr int NBLK = 116;                         // 112 bilateral + 4 spatial vols
constexpr int PPB  = (NT + NBLK - 1) / NBLK;      // 71 points/block, pointwise phases

static __device__ __forceinline__ float ex2(float x) {
    return __builtin_amdgcn_exp2f(x);
}

__constant__ float INVSQF[7] = {1.f, 1.f, 0.70710678f, 0.40824829f,
                                0.20412415f, 0.09128709f, 0.03726780f};
// ab -> (a,b) enumeration: for k=0..6, a=k..0, b=k-a  (must match contract order)
__constant__ int AB_A[28] = {0, 1,0, 2,1,0, 3,2,1,0, 4,3,2,1,0,
                             5,4,3,2,1,0, 6,5,4,3,2,1,0};
__constant__ int AB_B[28] = {0, 0,1, 0,1,2, 0,1,2,3, 0,1,2,3,4,
                             0,1,2,3,4,5, 0,1,2,3,4,5,6};

// ------------------------- custom grid barrier ------------------------------
// sync[0]          : monotone arrive counter (target = gen*NBLK)
// sync[16+g*16]    : go word for group g (g = bid&7), bumped by last arriver.
// All polling uses RELAXED fetch_add(0) — RMWs are device-coherent (m20) and
// emit NO cache ops. The one __threadfence() pair per block per barrier pays
// the L2 writeback/invalidate exactly once.
static __device__ __forceinline__ void gsync(unsigned* sync, unsigned gen) {
    __syncthreads();                      // all waves' stores drained (vmcnt 0)
    if (threadIdx.x == 0) {
        __threadfence();                  // release: wb this XCD's L2 once
        unsigned old = __hip_atomic_fetch_add(sync, 1u, __ATOMIC_RELAXED,
                                              __HIP_MEMORY_SCOPE_AGENT);
        if (old == gen * NBLK - 1u) {
            // last arriver: broadcast go to 8 padded words (fire-and-forget)
#pragma unroll
            for (int g = 0; g < 8; ++g)
                __hip_atomic_fetch_add(sync + 16 + g*16, 1u, __ATOMIC_RELAXED,
                                       __HIP_MEMORY_SCOPE_AGENT);
        } else {
            unsigned* go = sync + 16 + (blockIdx.x & 7) * 16;
            while (__hip_atomic_fetch_add(go, 0u, __ATOMIC_RELAXED,
                                          __HIP_MEMORY_SCOPE_AGENT) < gen)
                __builtin_amdgcn_s_sleep(2);
        }
        __threadfence();                  // acquire: inv L1/L2 once
    }
    __syncthreads();
}

// ---------------- separable 3-D Gaussian conv, 512-thread version -----------
// SP staged as SP[(n>>4)*17 + (n&15)]; caller stages, we sync first.
static __device__ __forceinline__ void conv3d_store512(float* SP,
                                                       float* __restrict__ outp,
                                                       int tid) {
    float g32[32];
#pragma unroll
    for (int d = 0; d < 32; d++) { float t = d * INVA; g32[d] = ex2(-0.5f*t*t); }
    __syncthreads();
    // z-pass: 512 rows (x,y), one per thread, stride 17
    {
        int r = tid;
        float v[16], acc[16];
#pragma unroll
        for (int z = 0; z < 16; z++) { v[z] = SP[r*17 + z]; acc[z] = 0.f; }
#pragma unroll
        for (int zp = 0; zp < 16; zp++)
#pragma unroll
            for (int z = 0; z < 16; z++) {
                int d = (z > zp) ? (z - zp) : (zp - z);
                acc[z] = fmaf(g32[d], v[zp], acc[z]);
            }
#pragma unroll
        for (int z = 0; z < 16; z++) SP[r*17 + z] = acc[z];
    }
    __syncthreads();
    // y-pass: 512 rows (x,z), one per thread, stride 17 between y's
    {
        int x = tid >> 4, z = tid & 15;
        int base = x * 272 + z;
        float v[16], acc[16];
#pragma unroll
        for (int y = 0; y < 16; y++) { v[y] = SP[base + y*17]; acc[y] = 0.f; }
#pragma unroll
        for (int yp = 0; yp < 16; yp++)
#pragma unroll
            for (int y = 0; y < 16; y++) {
                int d = (y > yp) ? (y - yp) : (yp - y);
                acc[y] = fmaf(g32[d], v[yp], acc[y]);
            }
#pragma unroll
        for (int y = 0; y < 16; y++) SP[base + y*17] = acc[y];
    }
    __syncthreads();
    // x-pass: 256 columns (y,z), 2 threads/column; h wave-uniform (tid>>8)
    // so all g32 indices stay compile-time constants (no scratch spill).
    {
        int c = tid & 255, h = tid >> 8;
        int base = (c >> 4) * 17 + (c & 15);     // 17*y + z
        float v[32];
#pragma unroll
        for (int xp = 0; xp < 32; xp++) v[xp] = SP[base + xp*272];
        float acc[16];
#pragma unroll
        for (int x0 = 0; x0 < 16; x0++) acc[x0] = 0.f;
        if (h == 0) {
#pragma unroll
            for (int xp = 0; xp < 32; xp++)
#pragma unroll
                for (int x0 = 0; x0 < 16; x0++) {
                    int d = (x0 > xp) ? (x0 - xp) : (xp - x0);
                    acc[x0] = fmaf(g32[d], v[xp], acc[x0]);
                }
#pragma unroll
            for (int x0 = 0; x0 < 16; x0++) outp[x0*256 + c] = acc[x0];
        } else {
#pragma unroll
            for (int xp = 0; xp < 32; xp++)
#pragma unroll
                for (int x0 = 0; x0 < 16; x0++) {
                    int x = x0 + 16;
                    int d = (x > xp) ? (x - xp) : (xp - x);
                    acc[x0] = fmaf(g32[d], v[xp], acc[x0]);
                }
#pragma unroll
            for (int x0 = 0; x0 < 16; x0++) outp[(x0+16)*256 + c] = acc[x0];
        }
    }
}

// ---------------- separable 3-D conv, 256-thread version (fallback path) ----
static __device__ __forceinline__ void conv3d_store256(float* SP,
                                                       float* __restrict__ outp,
                                                       int tid) {
    float g32[32];
#pragma unroll
    for (int d = 0; d < 32; d++) { float t = d * INVA; g32[d] = ex2(-0.5f*t*t); }
    __syncthreads();
#pragma unroll
    for (int rr = 0; rr < 2; rr++) {
        int r = tid + rr * 256;
        float v[16], acc[16];
#pragma unroll
        for (int z = 0; z < 16; z++) { v[z] = SP[r*17 + z]; acc[z] = 0.f; }
#pragma unroll
        for (int zp = 0; zp < 16; zp++)
#pragma unroll
            for (int z = 0; z < 16; z++) {
                int d = (z > zp) ? (z - zp) : (zp - z);
                acc[z] = fmaf(g32[d], v[zp], acc[z]);
            }
#pragma unroll
        for (int z = 0; z < 16; z++) SP[r*17 + z] = acc[z];
    }
    __syncthreads();
#pragma unroll
    for (int rr = 0; rr < 2; rr++) {
        int r = tid + rr * 256;
        int x = r >> 4, z = r & 15;
        int base = x * 272 + z;
        float v[16], acc[16];
#pragma unroll
        for (int y = 0; y < 16; y++) { v[y] = SP[base + y*17]; acc[y] = 0.f; }
#pragma unroll
        for (int yp = 0; yp < 16; yp++)
#pragma unroll
            for (int y = 0; y < 16; y++) {
                int d = (y > yp) ? (y - yp) : (yp - y);
                acc[y] = fmaf(g32[d], v[yp], acc[y]);
            }
#pragma unroll
        for (int y = 0; y < 16; y++) SP[base + y*17] = acc[y];
    }
    __syncthreads();
    {
        int base = (tid >> 4) * 17 + (tid & 15);
        float v[32], acc[32];
#pragma unroll
        for (int xp = 0; xp < 32; xp++) { v[xp] = SP[base + xp*272]; acc[xp] = 0.f; }
#pragma unroll
        for (int xp = 0; xp < 32; xp++)
#pragma unroll
            for (int x = 0; x < 32; x++) {
                int d = (x > xp) ? (x - xp) : (xp - x);
                acc[x] = fmaf(g32[d], v[xp], acc[x]);
            }
#pragma unroll
        for (int x = 0; x < 32; x++) outp[x*256 + tid] = acc[x];
    }
}

// ----------------------------- pointwise bodies -----------------------------
static __device__ __forceinline__ void init_point(float* __restrict__ W,
                                                  const float* __restrict__ lu,
                                                  int n) {
    float rs = 0.f;
#pragma unroll
    for (int ab = 0; ab < 28; ab++)
        rs = fmaf(W[(R_M+ab)*NT + n], W[(R_CV+ab)*NT + n], rs);
    float s1 = rsqrtf(rs);
    float s2 = W[R_S2*NT + n];
    W[R_S1*NT + n] = s1;
    float l0 = lu[n], l1 = lu[NT+n], l2 = lu[2*NT+n], l3 = lu[3*NT+n];
    float mx = fmaxf(fmaxf(l0,l1), fmaxf(l2,l3));
    float q0 = __expf(l0-mx), q1 = __expf(l1-mx), q2 = __expf(l2-mx), q3 = __expf(l3-mx);
    float inv = 1.f / (q0+q1+q2+q3);
    q0*=inv; q1*=inv; q2*=inv; q3*=inv;
    W[(R_U1+0)*NT+n]=q0*s1; W[(R_U1+1)*NT+n]=q1*s1; W[(R_U1+2)*NT+n]=q2*s1; W[(R_U1+3)*NT+n]=q3*s1;
    W[(R_U2+0)*NT+n]=q0*s2; W[(R_U2+1)*NT+n]=q1*s2; W[(R_U2+2)*NT+n]=q2*s2; W[(R_U2+3)*NT+n]=q3*s2;
}

static __device__ __forceinline__ void fuse_point(float* __restrict__ W,
        const float* __restrict__ lu, const float* __restrict__ compat,
        float* __restrict__ out, int n, int last) {
    float s1 = W[R_S1*NT + n], s2 = W[R_S2*NT + n];
    float q1[4] = {0.f, 0.f, 0.f, 0.f};
#pragma unroll
    for (int ab = 0; ab < 28; ab++) {
        float m = W[(R_M+ab)*NT + n];
#pragma unroll
        for (int c = 0; c < 4; c++)
            q1[c] = fmaf(m, W[(R_CV + ab*4 + c)*NT + n], q1[c]);
    }
    float comb[4];
#pragma unroll
    for (int c = 0; c < 4; c++)
        comb[c] = s1 * q1[c] + s2 * W[(R_CV + 112 + c)*NT + n];
    float q[4];
#pragma unroll
    for (int o = 0; o < 4; o++) {
        float upd = 0.f;
#pragma unroll
        for (int c = 0; c < 4; c++) upd = fmaf(compat[o*4+c], comb[c], upd);
        q[o] = lu[o*NT+n] - upd;
    }
    float mx = fmaxf(fmaxf(q[0],q[1]), fmaxf(q[2],q[3]));
    float sum = 0.f;
#pragma unroll
    for (int c = 0; c < 4; c++) { q[c] = __expf(q[c]-mx); sum += q[c]; }
    float inv = 1.f / sum;
    if (last) {
#pragma unroll
        for (int c = 0; c < 4; c++) out[c*NT+n] = q[c] * inv;
    } else {
#pragma unroll
        for (int c = 0; c < 4; c++) {
            float qq = q[c] * inv;
            W[(R_U1+c)*NT+n] = qq*s1;
            W[(R_U2+c)*NT+n] = qq*s2;
        }
    }
}

// ---------------------- zero the barrier flags (pre-kernel) -----------------
__global__ __launch_bounds__(256) void k_zero(float* __restrict__ W) {
    unsigned* sync = (unsigned*)(W + R_SY*NT);
    if (threadIdx.x < 256) sync[threadIdx.x] = 0u;
}

// --------------------------- the single persistent kernel -------------------
__global__ __launch_bounds__(512) void k_crf_all(const float* __restrict__ lu,
        const float* __restrict__ feat, const float* __restrict__ compat,
        float* __restrict__ out, float* __restrict__ W) {
    __shared__ float SP[512 * 17];
    const int bid = blockIdx.x, tid = threadIdx.x;
    unsigned* sync = (unsigned*)(W + R_SY*NT);
    unsigned gen = 0;

    // ---- phase A: blocks 0..27 build + conv their own basis row (norm pass);
    //               blocks 28..115 compute closed-form scale2.
    if (bid < 28) {
        const int a = AB_A[bid], b = AB_B[bid];
        const float ca = INVSQF[a], cb = INVSQF[b];
        for (int s = tid; s < NT; s += 512) {
            float g0 = feat[s] * 0.2f, g1 = feat[NT + s] * 0.2f;
            float eg = ex2(-0.5f * LOG2E * (g0*g0 + g1*g1));
            float pa = 1.f;
            for (int i = 0; i < a; i++) pa *= g0;   // a,b wave-uniform (blockIdx)
            float pb = 1.f;
            for (int i = 0; i < b; i++) pb *= g1;
            float v = eg * pa * ca * pb * cb;
            W[(R_M + bid)*NT + s] = v;
            SP[(s >> 4)*17 + (s & 15)] = v;
        }
        conv3d_store512(SP, W + (R_CV + bid)*NT, tid);
    } else {
        const int nb = (bid - 28) * 94 + tid;       // 88 blocks x 94 >= 8192
        if (tid < 94 && nb < NT) {
            int x = nb >> 8, y = (nb >> 4) & 15, z = nb & 15;
            float Sx = 0.f, Sy = 0.f, Sz = 0.f;
            for (int j = 0; j < 32; j++) { float d = (float)(x-j)*INVA; Sx += ex2(-0.5f*d*d); }
            for (int j = 0; j < 16; j++) { float d = (float)(y-j)*INVA; Sy += ex2(-0.5f*d*d); }
            for (int j = 0; j < 16; j++) { float d = (float)(z-j)*INVA; Sz += ex2(-0.5f*d*d); }
            W[R_S2*NT + nb] = rsqrtf(Sx * Sy * Sz);
        }
    }
    gsync(sync, ++gen);

    // ---- init: rowsum contract -> scale1, q0, u1, u2
    { int n = bid * PPB + tid; if (tid < PPB && n < NT) init_point(W, lu, n); }
    gsync(sync, ++gen);

    // ---- 5 mean-field iterations: conv(116 vols) -> fuse -> repeat
    for (int it = 0; it < 5; ++it) {
        {
            const int idx = bid;
            if (idx < 112) {
                const float* Mr = W + (R_M + (idx >> 2))*NT;
                const float* ur = W + (R_U1 + (idx & 3))*NT;
                for (int s = tid; s < NT; s += 512)
                    SP[(s >> 4)*17 + (s & 15)] = Mr[s] * ur[s];
            } else {
                const float* ur = W + (R_U2 + (idx - 112))*NT;
                for (int s = tid; s < NT; s += 512)
                    SP[(s >> 4)*17 + (s & 15)] = ur[s];
            }
            conv3d_store512(SP, W + (R_CV + idx)*NT, tid);
        }
        gsync(sync, ++gen);
        { int n = bid * PPB + tid; if (tid < PPB && n < NT) fuse_point(W, lu, compat, out, n, it == 4); }
        if (it < 4) gsync(sync, ++gen);
    }
}

// --------------------------- fallback multi-kernel path ---------------------
__global__ __launch_bounds__(256) void k_setup(const float* __restrict__ feat,
                                               float* __restrict__ W) {
    int n = blockIdx.x * 256 + threadIdx.x;
    float g0 = feat[n] * 0.2f, g1 = feat[NT + n] * 0.2f;
    float eg = ex2(-0.5f * LOG2E * (g0*g0 + g1*g1));
    float p0[7], p1[7];
    p0[0] = 1.f; p1[0] = 1.f;
#pragma unroll
    for (int i = 1; i < 7; i++) { p0[i] = p0[i-1]*g0; p1[i] = p1[i-1]*g1; }
    int ab = 0;
#pragma unroll
    for (int k = 0; k <= 6; k++)
#pragma unroll
        for (int a = k; a >= 0; a--) {
            int b = k - a;
            W[(R_M + ab)*NT + n] = eg * p0[a]*INVSQF[a] * p1[b]*INVSQF[b];
            ab++;
        }
    int x = n >> 8, y = (n >> 4) & 15, z = n & 15;
    float Sx = 0.f, Sy = 0.f, Sz = 0.f;
    for (int j = 0; j < 32; j++) { float d = (float)(x-j)*INVA; Sx += ex2(-0.5f*d*d); }
    for (int j = 0; j < 16; j++) { float d = (float)(y-j)*INVA; Sy += ex2(-0.5f*d*d); }
    for (int j = 0; j < 16; j++) { float d = (float)(z-j)*INVA; Sz += ex2(-0.5f*d*d); }
    W[R_S2*NT + n] = rsqrtf(Sx * Sy * Sz);
}

__global__ __launch_bounds__(256) void k_conv(const float* __restrict__ W,
                                              float* __restrict__ Wout, int mode) {
    __shared__ float SP[512 * 17];
    const int idx = blockIdx.x;
    const int tid = threadIdx.x;
    if (mode == 0) {
        const float* src = W + (R_M + idx) * NT;
        for (int s = tid; s < NT; s += 256)
            SP[(s >> 4)*17 + (s & 15)] = src[s];
    } else if (idx < 112) {
        const float* Mr = W + (R_M + (idx >> 2)) * NT;
        const float* ur = W + (R_U1 + (idx & 3)) * NT;
        for (int s = tid; s < NT; s += 256)
            SP[(s >> 4)*17 + (s & 15)] = Mr[s] * ur[s];
    } else {
        const float* ur = W + (R_U2 + (idx - 112)) * NT;
        for (int s = tid; s < NT; s += 256)
            SP[(s >> 4)*17 + (s & 15)] = ur[s];
    }
    conv3d_store256(SP, Wout + (R_CV + idx)*NT, tid);
}

__global__ __launch_bounds__(256) void k_init(float* __restrict__ W,
                                              const float* __restrict__ lu) {
    int n = blockIdx.x * 256 + threadIdx.x;
    init_point(W, lu, n);
}

__global__ __launch_bounds__(256) void k_fuse(float* __restrict__ W,
        const float* __restrict__ lu, const float* __restrict__ compat,
        float* __restrict__ out, int last) {
    int n = blockIdx.x * 256 + threadIdx.x;
    fuse_point(W, lu, compat, out, n, last);
}

// ---------------------------------------------------------------- driver
extern "C" void kernel_launch(void* const* d_in, const int* in_sizes, int n_in,
                              void* d_out, int out_size, void* d_ws, size_t ws_size,
                              hipStream_t stream) {
    const float* lu     = (const float*)d_in[0];
    const float* feat   = (const float*)d_in[1];
    const float* compat = (const float*)d_in[2];
    float* out = (float*)d_out;
    float* W   = (float*)d_ws;     // needs 158*NT*4 = 5.2 MB

    k_zero<<<dim3(1), dim3(256), 0, stream>>>(W);   // zero barrier flags

    void* args[] = {(void*)&lu, (void*)&feat, (void*)&compat, (void*)&out, (void*)&W};
    hipError_t rc = hipLaunchCooperativeKernel((const void*)k_crf_all,
                                               dim3(NBLK), dim3(512), args, 0, stream);
    if (rc != hipSuccess) {
        (void)hipGetLastError();   // clear, fall back to multi-launch path
        k_setup<<<dim3(32), dim3(256), 0, stream>>>(feat, W);
        k_conv <<<dim3(28), dim3(256), 0, stream>>>(W, W, 0);
        k_init <<<dim3(32), dim3(256), 0, stream>>>(W, lu);
        for (int it = 0; it < 5; it++) {
            k_conv<<<dim3(116), dim3(256), 0, stream>>>(W, W, 1);
            k_fuse<<<dim3(32),  dim3(256), 0, stream>>>(W, lu, compat, out, it == 4);
        }
    }
}

// Round 4
// 429.029 us; speedup vs baseline: 1.2892x; 1.0470x over previous
//
#include <hip/hip_runtime.h>
#include <math.h>

// CRF mean-field, fully factorized — NO O(N^2) pass.
// Single persistent kernel + FENCELESS grid barrier.
// Round 2/3 lesson: per-block __threadfence()/acquire-fences emit wbl2/inv
// (full-L2 writeback/invalidate) per block per barrier -> ~30 us/barrier L2
// thrash, 87 MB writes. Fix: NO fences at all. Cross-phase MUTABLE data
// (CV conv outputs, u1/u2) moves via relaxed AGENT-scope atomics (sc1 ->
// L3 coherence point, cross-XCD coherent). Read-only data (M rows, scale1/2,
// inputs) stays normally L2-cached across barriers (never invalidated).
// __syncthreads() drains vmcnt (store acks) before the arrive RMW -> ordering.
// Bilateral kernel rank-28 Taylor basis (degree 6), separable 3-D Gaussian
// convs, 5 mean-field iterations. N = 32*16*16 = 8192, C = 4.

constexpr int   NT    = 8192;
constexpr float LOG2E = 1.4426950408889634f;
constexpr float SQL2E = 1.2011224087864498f;     // sqrt(log2 e)
constexpr float INVA  = 0.2f * SQL2E;            // spatial prescale

// W rows (NT floats each):
//   0..27  : M[ab]   28..31 : sync flags area   32..35 u1[c]
//   36..39 u2[c]   40 scale1  41 scale2  42..157 conv outputs
constexpr int R_M = 0, R_SY = 28, R_U1 = 32, R_U2 = 36, R_S1 = 40, R_S2 = 41, R_CV = 42;
constexpr int NBLK = 116;                         // 112 bilateral + 4 spatial vols
constexpr int PPB  = (NT + NBLK - 1) / NBLK;      // 71 points/block, pointwise phases

static __device__ __forceinline__ float ex2(float x) {
    return __builtin_amdgcn_exp2f(x);
}

// Coherence-point (agent/sc1) access for cross-phase mutable data. Relaxed ->
// plain global_load/store with sc1 bits, NO buffer_inv / buffer_wbl2.
static __device__ __forceinline__ float ldcp(const float* p) {
    return __hip_atomic_load(p, __ATOMIC_RELAXED, __HIP_MEMORY_SCOPE_AGENT);
}
static __device__ __forceinline__ void stcp(float* p, float v) {
    __hip_atomic_store(p, v, __ATOMIC_RELAXED, __HIP_MEMORY_SCOPE_AGENT);
}

__constant__ float INVSQF[7] = {1.f, 1.f, 0.70710678f, 0.40824829f,
                                0.20412415f, 0.09128709f, 0.03726780f};
// ab -> (a,b) enumeration: for k=0..6, a=k..0, b=k-a  (must match contract order)
__constant__ int AB_A[28] = {0, 1,0, 2,1,0, 3,2,1,0, 4,3,2,1,0,
                             5,4,3,2,1,0, 6,5,4,3,2,1,0};
__constant__ int AB_B[28] = {0, 0,1, 0,1,2, 0,1,2,3, 0,1,2,3,4,
                             0,1,2,3,4,5, 0,1,2,3,4,5,6};

// ------------------------- fenceless grid barrier ---------------------------
// sync[0]       : monotone arrive counter (target = gen*NBLK)
// sync[16+g*16] : go word for group g (g = bid&7), bumped by last arriver.
// All atomics relaxed agent-scope: no cache maintenance. Data ordering comes
// from __syncthreads()'s vmcnt(0) drain (sc1 store acks from L3) before the
// arrive RMW, and sc1 reads after go hitting the same L3.
static __device__ __forceinline__ void gsync(unsigned* sync, unsigned gen) {
    __syncthreads();                      // drains vmcnt: sc1 stores acked at L3
    if (threadIdx.x == 0) {
        unsigned old = __hip_atomic_fetch_add(sync, 1u, __ATOMIC_RELAXED,
                                              __HIP_MEMORY_SCOPE_AGENT);
        if (old == gen * NBLK - 1u) {
            // last arriver: everyone else has arrived; broadcast go, proceed
#pragma unroll
            for (int g = 0; g < 8; ++g)
                __hip_atomic_fetch_add(sync + 16 + g*16, 1u, __ATOMIC_RELAXED,
                                       __HIP_MEMORY_SCOPE_AGENT);
        } else {
            unsigned* go = sync + 16 + (blockIdx.x & 7) * 16;
            while (__hip_atomic_fetch_add(go, 0u, __ATOMIC_RELAXED,
                                          __HIP_MEMORY_SCOPE_AGENT) < gen)
                __builtin_amdgcn_s_sleep(8);      // ~0.2 us backoff: few RMW polls
        }
    }
    __syncthreads();
}

// ---------------- separable 3-D Gaussian conv, 512-thread version -----------
// SP staged as SP[(n>>4)*17 + (n&15)]; caller stages, we sync first.
// Output written via stcp (sc1) — consumed cross-XCD next phase.
static __device__ __forceinline__ void conv3d_store512(float* SP,
                                                       float* __restrict__ outp,
                                                       int tid) {
    float g32[32];
#pragma unroll
    for (int d = 0; d < 32; d++) { float t = d * INVA; g32[d] = ex2(-0.5f*t*t); }
    __syncthreads();
    // z-pass: 512 rows (x,y), one per thread, stride 17
    {
        int r = tid;
        float v[16], acc[16];
#pragma unroll
        for (int z = 0; z < 16; z++) { v[z] = SP[r*17 + z]; acc[z] = 0.f; }
#pragma unroll
        for (int zp = 0; zp < 16; zp++)
#pragma unroll
            for (int z = 0; z < 16; z++) {
                int d = (z > zp) ? (z - zp) : (zp - z);
                acc[z] = fmaf(g32[d], v[zp], acc[z]);
            }
#pragma unroll
        for (int z = 0; z < 16; z++) SP[r*17 + z] = acc[z];
    }
    __syncthreads();
    // y-pass: 512 rows (x,z), one per thread, stride 17 between y's
    {
        int x = tid >> 4, z = tid & 15;
        int base = x * 272 + z;
        float v[16], acc[16];
#pragma unroll
        for (int y = 0; y < 16; y++) { v[y] = SP[base + y*17]; acc[y] = 0.f; }
#pragma unroll
        for (int yp = 0; yp < 16; yp++)
#pragma unroll
            for (int y = 0; y < 16; y++) {
                int d = (y > yp) ? (y - yp) : (yp - y);
                acc[y] = fmaf(g32[d], v[yp], acc[y]);
            }
#pragma unroll
        for (int y = 0; y < 16; y++) SP[base + y*17] = acc[y];
    }
    __syncthreads();
    // x-pass: 256 columns (y,z), 2 threads/column; h wave-uniform (tid>>8)
    // so all g32 indices stay compile-time constants (no scratch spill).
    {
        int c = tid & 255, h = tid >> 8;
        int base = (c >> 4) * 17 + (c & 15);     // 17*y + z
        float v[32];
#pragma unroll
        for (int xp = 0; xp < 32; xp++) v[xp] = SP[base + xp*272];
        float acc[16];
#pragma unroll
        for (int x0 = 0; x0 < 16; x0++) acc[x0] = 0.f;
        if (h == 0) {
#pragma unroll
            for (int xp = 0; xp < 32; xp++)
#pragma unroll
                for (int x0 = 0; x0 < 16; x0++) {
                    int d = (x0 > xp) ? (x0 - xp) : (xp - x0);
                    acc[x0] = fmaf(g32[d], v[xp], acc[x0]);
                }
#pragma unroll
            for (int x0 = 0; x0 < 16; x0++) stcp(&outp[x0*256 + c], acc[x0]);
        } else {
#pragma unroll
            for (int xp = 0; xp < 32; xp++)
#pragma unroll
                for (int x0 = 0; x0 < 16; x0++) {
                    int x = x0 + 16;
                    int d = (x > xp) ? (x - xp) : (xp - x);
                    acc[x0] = fmaf(g32[d], v[xp], acc[x0]);
                }
#pragma unroll
            for (int x0 = 0; x0 < 16; x0++) stcp(&outp[(x0+16)*256 + c], acc[x0]);
        }
    }
}

// ---------------- separable 3-D conv, 256-thread version (fallback path) ----
// Normal stores: fallback path relies on kernel-boundary coherence.
static __device__ __forceinline__ void conv3d_store256(float* SP,
                                                       float* __restrict__ outp,
                                                       int tid) {
    float g32[32];
#pragma unroll
    for (int d = 0; d < 32; d++) { float t = d * INVA; g32[d] = ex2(-0.5f*t*t); }
    __syncthreads();
#pragma unroll
    for (int rr = 0; rr < 2; rr++) {
        int r = tid + rr * 256;
        float v[16], acc[16];
#pragma unroll
        for (int z = 0; z < 16; z++) { v[z] = SP[r*17 + z]; acc[z] = 0.f; }
#pragma unroll
        for (int zp = 0; zp < 16; zp++)
#pragma unroll
            for (int z = 0; z < 16; z++) {
                int d = (z > zp) ? (z - zp) : (zp - z);
                acc[z] = fmaf(g32[d], v[zp], acc[z]);
            }
#pragma unroll
        for (int z = 0; z < 16; z++) SP[r*17 + z] = acc[z];
    }
    __syncthreads();
#pragma unroll
    for (int rr = 0; rr < 2; rr++) {
        int r = tid + rr * 256;
        int x = r >> 4, z = r & 15;
        int base = x * 272 + z;
        float v[16], acc[16];
#pragma unroll
        for (int y = 0; y < 16; y++) { v[y] = SP[base + y*17]; acc[y] = 0.f; }
#pragma unroll
        for (int yp = 0; yp < 16; yp++)
#pragma unroll
            for (int y = 0; y < 16; y++) {
                int d = (y > yp) ? (y - yp) : (yp - y);
                acc[y] = fmaf(g32[d], v[yp], acc[y]);
            }
#pragma unroll
        for (int y = 0; y < 16; y++) SP[base + y*17] = acc[y];
    }
    __syncthreads();
    {
        int base = (tid >> 4) * 17 + (tid & 15);
        float v[32], acc[32];
#pragma unroll
        for (int xp = 0; xp < 32; xp++) { v[xp] = SP[base + xp*272]; acc[xp] = 0.f; }
#pragma unroll
        for (int xp = 0; xp < 32; xp++)
#pragma unroll
            for (int x = 0; x < 32; x++) {
                int d = (x > xp) ? (x - xp) : (xp - x);
                acc[x] = fmaf(g32[d], v[xp], acc[x]);
            }
#pragma unroll
        for (int x = 0; x < 32; x++) outp[x*256 + tid] = acc[x];
    }
}

// ----------------------------- pointwise bodies -----------------------------
// COH=true: persistent-kernel path — mutable rows via sc1 atomics.
template <bool COH>
static __device__ __forceinline__ void init_point(float* __restrict__ W,
                                                  const float* __restrict__ lu,
                                                  int n) {
    float rs = 0.f;
#pragma unroll
    for (int ab = 0; ab < 28; ab++) {
        float cv = COH ? ldcp(&W[(R_CV+ab)*NT + n]) : W[(R_CV+ab)*NT + n];
        rs = fmaf(W[(R_M+ab)*NT + n], cv, rs);
    }
    float s1 = rsqrtf(rs);
    float s2 = W[R_S2*NT + n];
    if (COH) stcp(&W[R_S1*NT + n], s1); else W[R_S1*NT + n] = s1;
    float l0 = lu[n], l1 = lu[NT+n], l2 = lu[2*NT+n], l3 = lu[3*NT+n];
    float mx = fmaxf(fmaxf(l0,l1), fmaxf(l2,l3));
    float q0 = __expf(l0-mx), q1 = __expf(l1-mx), q2 = __expf(l2-mx), q3 = __expf(l3-mx);
    float inv = 1.f / (q0+q1+q2+q3);
    q0*=inv; q1*=inv; q2*=inv; q3*=inv;
    float u1v[4] = {q0*s1, q1*s1, q2*s1, q3*s1};
    float u2v[4] = {q0*s2, q1*s2, q2*s2, q3*s2};
#pragma unroll
    for (int c = 0; c < 4; c++) {
        if (COH) { stcp(&W[(R_U1+c)*NT+n], u1v[c]); stcp(&W[(R_U2+c)*NT+n], u2v[c]); }
        else     { W[(R_U1+c)*NT+n] = u1v[c];       W[(R_U2+c)*NT+n] = u2v[c]; }
    }
}

template <bool COH>
static __device__ __forceinline__ void fuse_point(float* __restrict__ W,
        const float* __restrict__ lu, const float* __restrict__ compat,
        float* __restrict__ out, int n, int last) {
    float s1 = W[R_S1*NT + n], s2 = W[R_S2*NT + n];   // read-only after init
    float q1[4] = {0.f, 0.f, 0.f, 0.f};
#pragma unroll
    for (int ab = 0; ab < 28; ab++) {
        float m = W[(R_M+ab)*NT + n];                 // read-only after phase A
#pragma unroll
        for (int c = 0; c < 4; c++) {
            float cv = COH ? ldcp(&W[(R_CV + ab*4 + c)*NT + n])
                           : W[(R_CV + ab*4 + c)*NT + n];
            q1[c] = fmaf(m, cv, q1[c]);
        }
    }
    float comb[4];
#pragma unroll
    for (int c = 0; c < 4; c++) {
        float cv2 = COH ? ldcp(&W[(R_CV + 112 + c)*NT + n])
                        : W[(R_CV + 112 + c)*NT + n];
        comb[c] = s1 * q1[c] + s2 * cv2;
    }
    float q[4];
#pragma unroll
    for (int o = 0; o < 4; o++) {
        float upd = 0.f;
#pragma unroll
        for (int c = 0; c < 4; c++) upd = fmaf(compat[o*4+c], comb[c], upd);
        q[o] = lu[o*NT+n] - upd;
    }
    float mx = fmaxf(fmaxf(q[0],q[1]), fmaxf(q[2],q[3]));
    float sum = 0.f;
#pragma unroll
    for (int c = 0; c < 4; c++) { q[c] = __expf(q[c]-mx); sum += q[c]; }
    float inv = 1.f / sum;
    if (last) {
#pragma unroll
        for (int c = 0; c < 4; c++) out[c*NT+n] = q[c] * inv;  // host sees via kernel-end flush
    } else {
#pragma unroll
        for (int c = 0; c < 4; c++) {
            float qq = q[c] * inv;
            if (COH) { stcp(&W[(R_U1+c)*NT+n], qq*s1); stcp(&W[(R_U2+c)*NT+n], qq*s2); }
            else     { W[(R_U1+c)*NT+n] = qq*s1;       W[(R_U2+c)*NT+n] = qq*s2; }
        }
    }
}

// ---------------------- zero the barrier flags (pre-kernel) -----------------
__global__ __launch_bounds__(256) void k_zero(float* __restrict__ W) {
    unsigned* sync = (unsigned*)(W + R_SY*NT);
    if (threadIdx.x < 256) sync[threadIdx.x] = 0u;
}

// --------------------------- the single persistent kernel -------------------
__global__ __launch_bounds__(512) void k_crf_all(const float* __restrict__ lu,
        const float* __restrict__ feat, const float* __restrict__ compat,
        float* __restrict__ out, float* __restrict__ W) {
    __shared__ float SP[512 * 17];
    const int bid = blockIdx.x, tid = threadIdx.x;
    unsigned* sync = (unsigned*)(W + R_SY*NT);
    unsigned gen = 0;

    // ---- phase A: blocks 0..27 build + conv their own basis row (norm pass);
    //               blocks 28..115 compute closed-form scale2.
    if (bid < 28) {
        const int a = AB_A[bid], b = AB_B[bid];
        const float ca = INVSQF[a], cb = INVSQF[b];
        for (int s = tid; s < NT; s += 512) {
            float g0 = feat[s] * 0.2f, g1 = feat[NT + s] * 0.2f;
            float eg = ex2(-0.5f * LOG2E * (g0*g0 + g1*g1));
            float pa = 1.f;
            for (int i = 0; i < a; i++) pa *= g0;   // a,b wave-uniform (blockIdx)
            float pb = 1.f;
            for (int i = 0; i < b; i++) pb *= g1;
            float v = eg * pa * ca * pb * cb;
            stcp(&W[(R_M + bid)*NT + s], v);        // sc1: fresh at first cached read
            SP[(s >> 4)*17 + (s & 15)] = v;
        }
        conv3d_store512(SP, W + (R_CV + bid)*NT, tid);
    } else {
        const int nb = (bid - 28) * 94 + tid;       // 88 blocks x 94 >= 8192
        if (tid < 94 && nb < NT) {
            int x = nb >> 8, y = (nb >> 4) & 15, z = nb & 15;
            float Sx = 0.f, Sy = 0.f, Sz = 0.f;
            for (int j = 0; j < 32; j++) { float d = (float)(x-j)*INVA; Sx += ex2(-0.5f*d*d); }
            for (int j = 0; j < 16; j++) { float d = (float)(y-j)*INVA; Sy += ex2(-0.5f*d*d); }
            for (int j = 0; j < 16; j++) { float d = (float)(z-j)*INVA; Sz += ex2(-0.5f*d*d); }
            stcp(&W[R_S2*NT + nb], rsqrtf(Sx * Sy * Sz));
        }
    }
    gsync(sync, ++gen);

    // ---- init: rowsum contract -> scale1, q0, u1, u2
    { int n = bid * PPB + tid; if (tid < PPB && n < NT) init_point<true>(W, lu, n); }
    gsync(sync, ++gen);

    // ---- 5 mean-field iterations: conv(116 vols) -> fuse -> repeat
    for (int it = 0; it < 5; ++it) {
        {
            const int idx = bid;
            if (idx < 112) {
                const float* Mr = W + (R_M + (idx >> 2))*NT;   // cached (read-only)
                float* ur = W + (R_U1 + (idx & 3))*NT;         // mutable: sc1
                for (int s = tid; s < NT; s += 512)
                    SP[(s >> 4)*17 + (s & 15)] = Mr[s] * ldcp(&ur[s]);
            } else {
                float* ur = W + (R_U2 + (idx - 112))*NT;
                for (int s = tid; s < NT; s += 512)
                    SP[(s >> 4)*17 + (s & 15)] = ldcp(&ur[s]);
            }
            conv3d_store512(SP, W + (R_CV + idx)*NT, tid);
        }
        gsync(sync, ++gen);
        { int n = bid * PPB + tid; if (tid < PPB && n < NT) fuse_point<true>(W, lu, compat, out, n, it == 4); }
        if (it < 4) gsync(sync, ++gen);
    }
}

// --------------------------- fallback multi-kernel path ---------------------
__global__ __launch_bounds__(256) void k_setup(const float* __restrict__ feat,
                                               float* __restrict__ W) {
    int n = blockIdx.x * 256 + threadIdx.x;
    float g0 = feat[n] * 0.2f, g1 = feat[NT + n] * 0.2f;
    float eg = ex2(-0.5f * LOG2E * (g0*g0 + g1*g1));
    float p0[7], p1[7];
    p0[0] = 1.f; p1[0] = 1.f;
#pragma unroll
    for (int i = 1; i < 7; i++) { p0[i] = p0[i-1]*g0; p1[i] = p1[i-1]*g1; }
    int ab = 0;
#pragma unroll
    for (int k = 0; k <= 6; k++)
#pragma unroll
        for (int a = k; a >= 0; a--) {
            int b = k - a;
            W[(R_M + ab)*NT + n] = eg * p0[a]*INVSQF[a] * p1[b]*INVSQF[b];
            ab++;
        }
    int x = n >> 8, y = (n >> 4) & 15, z = n & 15;
    float Sx = 0.f, Sy = 0.f, Sz = 0.f;
    for (int j = 0; j < 32; j++) { float d = (float)(x-j)*INVA; Sx += ex2(-0.5f*d*d); }
    for (int j = 0; j < 16; j++) { float d = (float)(y-j)*INVA; Sy += ex2(-0.5f*d*d); }
    for (int j = 0; j < 16; j++) { float d = (float)(z-j)*INVA; Sz += ex2(-0.5f*d*d); }
    W[R_S2*NT + n] = rsqrtf(Sx * Sy * Sz);
}

__global__ __launch_bounds__(256) void k_conv(const float* __restrict__ W,
                                              float* __restrict__ Wout, int mode) {
    __shared__ float SP[512 * 17];
    const int idx = blockIdx.x;
    const int tid = threadIdx.x;
    if (mode == 0) {
        const float* src = W + (R_M + idx) * NT;
        for (int s = tid; s < NT; s += 256)
            SP[(s >> 4)*17 + (s & 15)] = src[s];
    } else if (idx < 112) {
        const float* Mr = W + (R_M + (idx >> 2)) * NT;
        const float* ur = W + (R_U1 + (idx & 3)) * NT;
        for (int s = tid; s < NT; s += 256)
            SP[(s >> 4)*17 + (s & 15)] = Mr[s] * ur[s];
    } else {
        const float* ur = W + (R_U2 + (idx - 112)) * NT;
        for (int s = tid; s < NT; s += 256)
            SP[(s >> 4)*17 + (s & 15)] = ur[s];
    }
    conv3d_store256(SP, Wout + (R_CV + idx)*NT, tid);
}

__global__ __launch_bounds__(256) void k_init(float* __restrict__ W,
                                              const float* __restrict__ lu) {
    int n = blockIdx.x * 256 + threadIdx.x;
    init_point<false>(W, lu, n);
}

__global__ __launch_bounds__(256) void k_fuse(float* __restrict__ W,
        const float* __restrict__ lu, const float* __restrict__ compat,
        float* __restrict__ out, int last) {
    int n = blockIdx.x * 256 + threadIdx.x;
    fuse_point<false>(W, lu, compat, out, n, last);
}

// ---------------------------------------------------------------- driver
extern "C" void kernel_launch(void* const* d_in, const int* in_sizes, int n_in,
                              void* d_out, int out_size, void* d_ws, size_t ws_size,
                              hipStream_t stream) {
    const float* lu     = (const float*)d_in[0];
    const float* feat   = (const float*)d_in[1];
    const float* compat = (const float*)d_in[2];
    float* out = (float*)d_out;
    float* W   = (float*)d_ws;     // needs 158*NT*4 = 5.2 MB

    k_zero<<<dim3(1), dim3(256), 0, stream>>>(W);   // zero barrier flags

    void* args[] = {(void*)&lu, (void*)&feat, (void*)&compat, (void*)&out, (void*)&W};
    hipError_t rc = hipLaunchCooperativeKernel((const void*)k_crf_all,
                                               dim3(NBLK), dim3(512), args, 0, stream);
    if (rc != hipSuccess) {
        (void)hipGetLastError();   // clear, fall back to multi-launch path
        k_setup<<<dim3(32), dim3(256), 0, stream>>>(feat, W);
        k_conv <<<dim3(28), dim3(256), 0, stream>>>(W, W, 0);
        k_init <<<dim3(32), dim3(256), 0, stream>>>(W, lu);
        for (int it = 0; it < 5; it++) {
            k_conv<<<dim3(116), dim3(256), 0, stream>>>(W, W, 1);
            k_fuse<<<dim3(32),  dim3(256), 0, stream>>>(W, lu, compat, out, it == 4);
        }
    }
}